// Round 8
// baseline (203.884 us; speedup 1.0000x reference)
//
#include <hip/hip_runtime.h>
#include <hip/hip_bf16.h>

#define EDIM 128
#define MDIM 8
#define ADIM 64
#define NFR  50
#define NCOL (NFR * MDIM)   // 400
#define NSLICE 64           // contention slices for softmax denominator atomics

typedef __attribute__((ext_vector_type(8))) short short8;
typedef __attribute__((ext_vector_type(4))) float f32x4;
typedef __attribute__((ext_vector_type(4))) unsigned uint4v;

__device__ __forceinline__ float waveReduceSum(float v) {
    #pragma unroll
    for (int s = 32; s >= 1; s >>= 1) v += __shfl_xor(v, s, 64);
    return v;
}
// packed f32->bf16 (RNE): compiler emits v_cvt_pk_bf16_f32
__device__ __forceinline__ unsigned cvt2u(float lo, float hi) {
    union { __hip_bfloat162 h; unsigned u; } cv;
    cv.h = __float22bfloat162_rn(float2{lo, hi});
    return cv.u;
}
__device__ __forceinline__ short8 pack8(float4 a, float4 b) {
    union { uint4v u; short8 s; } cv;
    cv.u[0] = cvt2u(a.x, a.y);
    cv.u[1] = cvt2u(a.z, a.w);
    cv.u[2] = cvt2u(b.x, b.y);
    cv.u[3] = cvt2u(b.z, b.w);
    return cv.s;
}
__device__ __forceinline__ short f2bf(float x) {
    unsigned u = __float_as_uint(x);
    u += 0x7FFFu + ((u >> 16) & 1u);
    return (short)(u >> 16);
}
__device__ __forceinline__ float bf2f(short s) {
    return __uint_as_float(((unsigned)(unsigned short)s) << 16);
}
// Swizzled A-frag layout (k3 only). Block (Mt=r>>4, Kt=e>>5) of 512 shorts;
// within it slot = (q*16+(r&15)) ^ (q<<1), q=(e>>3)&3.
__device__ __forceinline__ int fragOff(int r, int e) {   // e multiple of 8
    int q = (e >> 3) & 3;
    int slot = (q * 16 + (r & 15)) ^ (q << 1);
    int block = ((r >> 4) << 2) | (e >> 5);
    return (block * 64 + slot) * 8;
}
__device__ __forceinline__ int slotR(int l) { return l ^ (((l >> 4) & 3) << 1); }

// k0: pre-pack WA (B-frags 4Nt x 4Kt) and Key (4Kt, N padded 8->16 with 0);
// also zero the softmax-denominator slices (harness poisons ws each iter).
__global__ __launch_bounds__(256)
void k0_prep(const float* __restrict__ WA, const float* __restrict__ Key,
             short* __restrict__ WAfrag, short* __restrict__ Keyfrag,
             float* __restrict__ Ssum)
{
    int t = blockIdx.x * 256 + threadIdx.x;
    for (int i = t; i < NSLICE * NCOL; i += 5 * 256) Ssum[i] = 0.f;
    if (t < 1024) {
        int lane = t & 63;
        int Kt = (t >> 6) & 3;
        int Nt = t >> 8;
        int n  = Nt * 16 + (lane & 15);
        int k0 = Kt * 32 + (lane >> 4) * 8;
        short8 v;
        #pragma unroll
        for (int j = 0; j < 8; ++j) v[j] = f2bf(WA[(size_t)(k0 + j) * ADIM + n]);
        *(short8*)(WAfrag + (size_t)t * 8) = v;
    } else if (t < 1280) {
        int i = t - 1024;
        int lane = i & 63;
        int Kt = i >> 6;
        int n  = lane & 15;
        int k0 = Kt * 32 + (lane >> 4) * 8;
        short8 v;
        #pragma unroll
        for (int j = 0; j < 8; ++j)
            v[j] = (n < MDIM) ? f2bf(Key[(size_t)(k0 + j) * MDIM + n]) : (short)0;
        *(short8*)(Keyfrag + (size_t)i * 8) = v;
    }
}

// k1: one wave per b (full 4096-block grid preserved), 2-deep Kt gather
// pipeline: issue Kt+1's 8 b128 gathers into the alternate register buffer,
// sched_barrier, consume Kt. 16 loads in flight/wave at ~120 VGPR.
__global__ __launch_bounds__(64, 4)
void k1_attkey(const int* __restrict__ input_u, const int* __restrict__ input_uf,
               const float* __restrict__ uidW, const short* __restrict__ Keyfrag,
               float* __restrict__ att_key, float* __restrict__ Ssum,
               int user_num)
{
    __shared__ float uidn[EDIM];   // 512 B
    __shared__ float invL[64];     // 256 B
    const int l = threadIdx.x;
    const int b = blockIdx.x;

    // earliest loads first so their waits don't drain the gather queue
    const int u = input_u[b];
    int ufv = (l < NFR) ? input_uf[(size_t)b * NFR + l] : user_num;
    float x0 = uidW[(size_t)u * EDIM + l];
    float x1 = uidW[(size_t)u * EDIM + 64 + l];

    // friend ids for my 4 A-frag rows: f = Mt*16 + (l&15)
    // (rows 50..63 -> some uidW row; their MFMA output rows are discarded)
    int fid[4];
    #pragma unroll
    for (int Mt = 0; Mt < 4; ++Mt)
        fid[Mt] = __shfl(ufv, Mt * 16 + (l & 15), 64);
    const int eo = (l >> 4) * 8;    // my k-octet within each 32-wide K block

    float4 gaA[4], gbA[4], gaB[4], gbB[4];
    // issue Kt=0 gathers + Keyfrag loads up front
    #pragma unroll
    for (int Mt = 0; Mt < 4; ++Mt) {
        const float* fp = uidW + (size_t)fid[Mt] * EDIM + eo;
        gaA[Mt] = *(const float4*)fp;
        gbA[Mt] = *(const float4*)(fp + 4);
    }
    short8 kb0 = *(const short8*)(Keyfrag + (size_t)(0 * 64 + l) * 8);
    short8 kb1 = *(const short8*)(Keyfrag + (size_t)(1 * 64 + l) * 8);
    short8 kb2 = *(const short8*)(Keyfrag + (size_t)(2 * 64 + l) * 8);
    short8 kb3 = *(const short8*)(Keyfrag + (size_t)(3 * 64 + l) * 8);

    // uid L2-normalize (overlaps with the in-flight gathers)
    float s = waveReduceSum(x0 * x0 + x1 * x1);
    float uinv = 1.0f / fmaxf(sqrtf(s), 1e-12f);
    uidn[l] = x0 * uinv;
    uidn[64 + l] = x1 * uinv;
    __builtin_amdgcn_wave_barrier();

    f32x4 acc[4];
    #pragma unroll
    for (int Mt = 0; Mt < 4; ++Mt) acc[Mt] = (f32x4){0.f, 0.f, 0.f, 0.f};
    float fss[4] = {0.f, 0.f, 0.f, 0.f};

    auto issue = [&](int Kt, float4 (&ga)[4], float4 (&gb)[4]) {
        #pragma unroll
        for (int Mt = 0; Mt < 4; ++Mt) {
            const float* fp = uidW + (size_t)fid[Mt] * EDIM + Kt * 32 + eo;
            ga[Mt] = *(const float4*)fp;
            gb[Mt] = *(const float4*)(fp + 4);
        }
    };
    auto comp = [&](int Kt, short8 kbv, float4 (&ga)[4], float4 (&gb)[4]) {
        float4 un0 = *(const float4*)&uidn[Kt * 32 + eo];
        float4 un1 = *(const float4*)&uidn[Kt * 32 + eo + 4];
        float4 kpa, kpb;
        kpa.x = un0.x * bf2f(kbv[0]); kpa.y = un0.y * bf2f(kbv[1]);
        kpa.z = un0.z * bf2f(kbv[2]); kpa.w = un0.w * bf2f(kbv[3]);
        kpb.x = un1.x * bf2f(kbv[4]); kpb.y = un1.y * bf2f(kbv[5]);
        kpb.z = un1.z * bf2f(kbv[6]); kpb.w = un1.w * bf2f(kbv[7]);
        short8 kbp = pack8(kpa, kpb);
        #pragma unroll
        for (int Mt = 0; Mt < 4; ++Mt) {
            fss[Mt] += ga[Mt].x*ga[Mt].x + ga[Mt].y*ga[Mt].y
                     + ga[Mt].z*ga[Mt].z + ga[Mt].w*ga[Mt].w
                     + gb[Mt].x*gb[Mt].x + gb[Mt].y*gb[Mt].y
                     + gb[Mt].z*gb[Mt].z + gb[Mt].w*gb[Mt].w;
            short8 a = pack8(ga[Mt], gb[Mt]);
            acc[Mt] = __builtin_amdgcn_mfma_f32_16x16x32_bf16(a, kbp, acc[Mt], 0, 0, 0);
        }
    };

    issue(1, gaB, gbB);
    __builtin_amdgcn_sched_barrier(0);
    comp(0, kb0, gaA, gbA);
    issue(2, gaA, gbA);
    __builtin_amdgcn_sched_barrier(0);
    comp(1, kb1, gaB, gbB);
    issue(3, gaB, gbB);
    __builtin_amdgcn_sched_barrier(0);
    comp(2, kb2, gaA, gbA);
    comp(3, kb3, gaB, gbB);

    // per-row 1/||fe|| with mask folded in; route to output-row lanes via LDS
    #pragma unroll
    for (int Mt = 0; Mt < 4; ++Mt) {
        float t = fss[Mt];
        t += __shfl_xor(t, 16, 64);
        t += __shfl_xor(t, 32, 64);
        int f = Mt * 16 + (l & 15);
        float fn = (f < NFR && fid[Mt] != user_num) ? 1.f : 0.f;
        invL[f] = fn / fmaxf(sqrtf(t), 1e-12f);   // 4 same-value writers, benign
    }
    __builtin_amdgcn_wave_barrier();

    const int m = l & 15;
    if (m < MDIM) {
        float* Ss = Ssum + (size_t)(b & (NSLICE - 1)) * NCOL;
        #pragma unroll
        for (int Mt = 0; Mt < 4; ++Mt) {
            const int fbase = Mt * 16 + (l >> 4) * 4;
            #pragma unroll
            for (int r = 0; r < 4; ++r) {
                int f = fbase + r;
                if (f < NFR) {
                    float val = acc[Mt][r] * invL[f];
                    att_key[((size_t)b * NFR + f) * MDIM + m] = val;
                    // masked rows -> val==0 -> exp(0)=1, matching reference
                    // softmax(axis=0) denominator semantics
                    atomicAdd(&Ss[f * MDIM + m], __expf(val));
                }
            }
        }
    }
}

// k2b: merge NSLICE partials per column -> inv denominator
__global__ __launch_bounds__(256)
void k2b_merge(const float* __restrict__ Ssum, float* __restrict__ ise)
{
    int col = blockIdx.x * 256 + threadIdx.x;
    if (col >= NCOL) return;
    float S = 0.f;
    #pragma unroll
    for (int s = 0; s < NSLICE; ++s) S += Ssum[s * NCOL + col];
    ise[col] = 1.0f / S;
}

// k3: wave-per-b, barrier-free (R6-proven). am -> f2 frag -> 64 MFMAs ->
// fold -> j -> friend sum -> score. cvt_pk conversions; affine LDS offsets.
__global__ __launch_bounds__(256, 2)
void k3_final(const int* __restrict__ input_u, const int* __restrict__ input_i,
              const int* __restrict__ input_uf, const float* __restrict__ uidW,
              const float* __restrict__ iidW, const float* __restrict__ i_bias,
              const float* __restrict__ Mem, const short* __restrict__ WAfrag,
              const float* __restrict__ BA, const float* __restrict__ U_omega,
              const float* __restrict__ att_key, const float* __restrict__ ise,
              float* __restrict__ out, int user_num, int B)
{
    __shared__ short f2F4[4][64 * EDIM];   // 64 KB
    __shared__ float amL4[4][NCOL];        // 6.25 KB
    __shared__ float jxL4[4][64];          // 1 KB
    const int w = threadIdx.x >> 6, l = threadIdx.x & 63;
    const int b = blockIdx.x * 4 + w;
    if (b >= B) return;
    short* f2F = f2F4[w];
    float* amL = amL4[w];
    float* jxL = jxL4[w];

    const int u = input_u[b];
    const int ii = input_i[b];
    const float ib = i_bias[ii];
    int ufv = (l < NFR) ? input_uf[(size_t)b * NFR + l] : user_num;

    const int kg = l & 15, fl = l >> 4;
    const int e0 = kg * 8;

    // am = fn * exp(att_key) * ise  (max-free)
    #pragma unroll
    for (int c = 0; c < 7; ++c) {
        int i = l + 64 * c;
        if (i < NCOL) {
            float ak = att_key[(size_t)b * NCOL + i];
            int fid = __shfl(ufv, i >> 3, 64);
            amL[i] = (fid != user_num) ? __expf(ak) * ise[i] : 0.f;
        }
    }

    float4 mA[MDIM], mB[MDIM];            // Mem slice for this lane's e-octet
    #pragma unroll
    for (int m = 0; m < MDIM; ++m) {
        mA[m] = *(const float4*)&Mem[m * EDIM + e0];
        mB[m] = *(const float4*)&Mem[m * EDIM + e0 + 4];
    }
    __builtin_amdgcn_wave_barrier();

    // phase 1: f2 = (am x Mem) * fe -> swizzled frag (all 64 rows written)
    // f = 16*hi + 4*lo + fl; per-(hi,lo) affine LDS offsets
    #pragma unroll
    for (int hi = 0; hi < 4; ++hi) {
        #pragma unroll
        for (int lo = 0; lo < 4; ++lo) {
            int f = hi * 16 + lo * 4 + fl;
            short8 outv = {0, 0, 0, 0, 0, 0, 0, 0};
            if (f < NFR) {
                int fid = __shfl(ufv, f, 64);
                const float* fp = uidW + (size_t)fid * EDIM + e0;
                float4 g0 = *(const float4*)fp;
                float4 g1 = *(const float4*)(fp + 4);
                float4 am0 = *(const float4*)&amL[f * 8];
                float4 am1 = *(const float4*)&amL[f * 8 + 4];
                float4 fa = {0.f, 0.f, 0.f, 0.f}, fb = {0.f, 0.f, 0.f, 0.f};
                #pragma unroll
                for (int m = 0; m < 4; ++m) {
                    float c0 = (&am0.x)[m], c1 = (&am1.x)[m];
                    fa.x += c0 * mA[m].x + c1 * mA[m + 4].x;
                    fa.y += c0 * mA[m].y + c1 * mA[m + 4].y;
                    fa.z += c0 * mA[m].z + c1 * mA[m + 4].z;
                    fa.w += c0 * mA[m].w + c1 * mA[m + 4].w;
                    fb.x += c0 * mB[m].x + c1 * mB[m + 4].x;
                    fb.y += c0 * mB[m].y + c1 * mB[m + 4].y;
                    fb.z += c0 * mB[m].z + c1 * mB[m + 4].z;
                    fb.w += c0 * mB[m].w + c1 * mB[m + 4].w;
                }
                // masked friends: am==0 -> fa=fb=0 -> f2=0 (matches reference)
                float4 pA, pB;
                pA.x = fa.x * g0.x; pA.y = fa.y * g0.y;
                pA.z = fa.z * g0.z; pA.w = fa.w * g0.w;
                pB.x = fb.x * g1.x; pB.y = fb.y * g1.y;
                pB.z = fb.z * g1.z; pB.w = fb.w * g1.w;
                outv = pack8(pA, pB);
            }
            *(short8*)&f2F[fragOff(f, e0)] = outv;
        }
    }
    __builtin_amdgcn_wave_barrier();

    // phase 2: h = f2(64x128) x WA(128x64), 64 MFMAs per wave
    const int sl = slotR(l);
    f32x4 acc[4][4];
    #pragma unroll
    for (int Mt = 0; Mt < 4; ++Mt)
        #pragma unroll
        for (int Nt = 0; Nt < 4; ++Nt) acc[Mt][Nt] = (f32x4){0.f, 0.f, 0.f, 0.f};
    #pragma unroll
    for (int Kt = 0; Kt < 4; ++Kt) {
        short8 a[4];
        #pragma unroll
        for (int Mt = 0; Mt < 4; ++Mt)
            a[Mt] = *(const short8*)&f2F[(((Mt << 2) | Kt) * 64 + sl) * 8];
        #pragma unroll
        for (int Nt = 0; Nt < 4; ++Nt) {
            short8 bf = *(const short8*)(WAfrag + (size_t)(((Nt << 2) | Kt) * 64 + l) * 8);
            #pragma unroll
            for (int Mt = 0; Mt < 4; ++Mt)
                acc[Mt][Nt] = __builtin_amdgcn_mfma_f32_16x16x32_bf16(a[Mt], bf, acc[Mt][Nt], 0, 0, 0);
        }
    }

    // phase 3: fold relu(h+BA)*U_omega over all 64 cols -> per-friend p
    float ba4[4], uo4[4];
    #pragma unroll
    for (int Nt = 0; Nt < 4; ++Nt) {
        ba4[Nt] = BA[Nt * 16 + kg];
        uo4[Nt] = U_omega[Nt * 16 + kg];
    }
    float v[16];
    #pragma unroll
    for (int Mt = 0; Mt < 4; ++Mt)
        #pragma unroll
        for (int r = 0; r < 4; ++r) {
            float sv = 0.f;
            #pragma unroll
            for (int Nt = 0; Nt < 4; ++Nt)
                sv += fmaxf(acc[Mt][Nt][r] + ba4[Nt], 0.f) * uo4[Nt];
            v[Mt * 4 + r] = sv;
        }

    const bool c0 = l & 1, c1 = l & 2, c2 = l & 4, c3 = l & 8;
    #pragma unroll
    for (int k = 0; k < 8; ++k) {
        float lo = v[k], hi = v[k + 8];
        float send = c0 ? lo : hi;
        float recv = __shfl_xor(send, 1, 64);
        v[k] = c0 ? (hi + recv) : (lo + recv);
    }
    #pragma unroll
    for (int k = 0; k < 4; ++k) {
        float lo = v[k], hi = v[k + 4];
        float send = c1 ? lo : hi;
        float recv = __shfl_xor(send, 2, 64);
        v[k] = c1 ? (hi + recv) : (lo + recv);
    }
    #pragma unroll
    for (int k = 0; k < 2; ++k) {
        float lo = v[k], hi = v[k + 2];
        float send = c2 ? lo : hi;
        float recv = __shfl_xor(send, 4, 64);
        v[k] = c2 ? (hi + recv) : (lo + recv);
    }
    {
        float lo = v[0], hi = v[1];
        float send = c3 ? lo : hi;
        float recv = __shfl_xor(send, 8, 64);
        v[0] = c3 ? (hi + recv) : (lo + recv);
    }
    const int vIdx = ((l & 1) << 3) | ((l & 2) << 1) | ((l & 4) >> 1) | ((l & 8) >> 3);
    const int fLane = (vIdx >> 2) * 16 + (l >> 4) * 4 + (vIdx & 3);

    int ufF = __shfl(ufv, fLane, 64);
    float jv = 0.f;
    if (fLane < NFR && ufF != user_num) jv = __expf(v[0]);
    jxL[fLane] = jv;
    float winv = 1.0f / (waveReduceSum(jv) + 1e-8f);
    __builtin_amdgcn_wave_barrier();

    // phase 4: friend-weighted sum of f2 (pad rows are zero, jx pad = 0)
    float pa[8] = {0.f, 0.f, 0.f, 0.f, 0.f, 0.f, 0.f, 0.f};
    #pragma unroll
    for (int hi = 0; hi < 4; ++hi) {
        #pragma unroll
        for (int lo = 0; lo < 4; ++lo) {
            int f = hi * 16 + lo * 4 + fl;
            float jf = jxL[f];
            short8 vv = *(const short8*)&f2F[fragOff(f, e0)];
            #pragma unroll
            for (int j = 0; j < 8; ++j) pa[j] += jf * bf2f(vv[j]);
        }
    }
    #pragma unroll
    for (int j = 0; j < 8; ++j) {
        pa[j] += __shfl_xor(pa[j], 16, 64);
        pa[j] += __shfl_xor(pa[j], 32, 64);
    }

    // epilogue: score = sum_e (uid+friend)*iid + i_bias (4x duplicated -> *0.25)
    const float* up = uidW + (size_t)u * EDIM + e0;
    const float* ip = iidW + (size_t)ii * EDIM + e0;
    float4 u0 = *(const float4*)up;
    float4 u1 = *(const float4*)(up + 4);
    float4 i0 = *(const float4*)ip;
    float4 i1 = *(const float4*)(ip + 4);
    float sc = 0.f;
    #pragma unroll
    for (int j = 0; j < 4; ++j) {
        sc += ((&u0.x)[j] + pa[j] * winv) * (&i0.x)[j];
        sc += ((&u1.x)[j] + pa[j + 4] * winv) * (&i1.x)[j];
    }
    float red = waveReduceSum(sc);
    if (l == 0) out[b] = red * 0.25f + ib;
}

extern "C" void kernel_launch(void* const* d_in, const int* in_sizes, int n_in,
                              void* d_out, int out_size, void* d_ws, size_t ws_size,
                              hipStream_t stream)
{
    const int*   input_u  = (const int*)d_in[0];
    const int*   input_i  = (const int*)d_in[1];
    const int*   input_uf = (const int*)d_in[2];
    const float* uidW     = (const float*)d_in[3];
    const float* iidW     = (const float*)d_in[4];
    const float* i_bias   = (const float*)d_in[5];
    const float* Key      = (const float*)d_in[6];
    const float* Mem      = (const float*)d_in[7];
    const float* WA       = (const float*)d_in[8];
    const float* BA       = (const float*)d_in[9];
    const float* U_om     = (const float*)d_in[10];

    const int B = in_sizes[0];
    const int user_num = in_sizes[3] / EDIM - 1;

    float* att  = (float*)d_ws;                                  // B*400
    float* Ssum = att + (size_t)B * NCOL;                        // 64*400
    float* ise  = Ssum + NSLICE * NCOL;                          // 400
    short* WAfrag  = (short*)(ise + NCOL);                       // 8192
    short* Keyfrag = WAfrag + 4 * 4 * 64 * 8;                    // 2048

    const int nb3 = (B + 3) / 4;
    k0_prep<<<5, 256, 0, stream>>>(WA, Key, WAfrag, Keyfrag, Ssum);
    k1_attkey<<<B, 64, 0, stream>>>(input_u, input_uf, uidW, Keyfrag, att,
                                    Ssum, user_num);
    k2b_merge<<<2, 256, 0, stream>>>(Ssum, ise);
    k3_final<<<nb3, 256, 0, stream>>>(input_u, input_i, input_uf, uidW, iidW, i_bias,
                                      Mem, WAfrag, BA, U_om, att, ise,
                                      (float*)d_out, user_num, B);
}

// Round 9
// 168.428 us; speedup vs baseline: 1.2105x; 1.2105x over previous
//
#include <hip/hip_runtime.h>
#include <hip/hip_bf16.h>

#define EDIM 128
#define MDIM 8
#define ADIM 64
#define NFR  50
#define NCOL (NFR * MDIM)   // 400
#define NSLICE 64           // contention slices for softmax denominator atomics

typedef __attribute__((ext_vector_type(8))) short short8;
typedef __attribute__((ext_vector_type(4))) float f32x4;
typedef __attribute__((ext_vector_type(4))) unsigned uint4v;

__device__ __forceinline__ float waveReduceSum(float v) {
    #pragma unroll
    for (int s = 32; s >= 1; s >>= 1) v += __shfl_xor(v, s, 64);
    return v;
}
// packed f32->bf16 (RNE): compiler emits v_cvt_pk_bf16_f32
__device__ __forceinline__ unsigned cvt2u(float lo, float hi) {
    union { __hip_bfloat162 h; unsigned u; } cv;
    cv.h = __float22bfloat162_rn(float2{lo, hi});
    return cv.u;
}
__device__ __forceinline__ short8 pack8(float4 a, float4 b) {
    union { uint4v u; short8 s; } cv;
    cv.u[0] = cvt2u(a.x, a.y);
    cv.u[1] = cvt2u(a.z, a.w);
    cv.u[2] = cvt2u(b.x, b.y);
    cv.u[3] = cvt2u(b.z, b.w);
    return cv.s;
}
__device__ __forceinline__ short f2bf(float x) {
    unsigned u = __float_as_uint(x);
    u += 0x7FFFu + ((u >> 16) & 1u);
    return (short)(u >> 16);
}
__device__ __forceinline__ float bf2f(short s) {
    return __uint_as_float(((unsigned)(unsigned short)s) << 16);
}
// Swizzled A-frag layout (k3 only). Block (Mt=r>>4, Kt=e>>5) of 512 shorts;
// within it slot = (q*16+(r&15)) ^ (q<<1), q=(e>>3)&3.
__device__ __forceinline__ int fragOff(int r, int e) {   // e multiple of 8
    int q = (e >> 3) & 3;
    int slot = (q * 16 + (r & 15)) ^ (q << 1);
    int block = ((r >> 4) << 2) | (e >> 5);
    return (block * 64 + slot) * 8;
}
__device__ __forceinline__ int slotR(int l) { return l ^ (((l >> 4) & 3) << 1); }

// k0: pre-pack WA (B-frags 4Nt x 4Kt) and Key (4Kt, N padded 8->16 with 0);
// also zero the softmax-denominator slices (harness poisons ws each iter).
__global__ __launch_bounds__(256)
void k0_prep(const float* __restrict__ WA, const float* __restrict__ Key,
             short* __restrict__ WAfrag, short* __restrict__ Keyfrag,
             float* __restrict__ Ssum)
{
    int t = blockIdx.x * 256 + threadIdx.x;
    for (int i = t; i < NSLICE * NCOL; i += 5 * 256) Ssum[i] = 0.f;
    if (t < 1024) {
        int lane = t & 63;
        int Kt = (t >> 6) & 3;
        int Nt = t >> 8;
        int n  = Nt * 16 + (lane & 15);
        int k0 = Kt * 32 + (lane >> 4) * 8;
        short8 v;
        #pragma unroll
        for (int j = 0; j < 8; ++j) v[j] = f2bf(WA[(size_t)(k0 + j) * ADIM + n]);
        *(short8*)(WAfrag + (size_t)t * 8) = v;
    } else if (t < 1280) {
        int i = t - 1024;
        int lane = i & 63;
        int Kt = i >> 6;
        int n  = lane & 15;
        int k0 = Kt * 32 + (lane >> 4) * 8;
        short8 v;
        #pragma unroll
        for (int j = 0; j < 8; ++j)
            v[j] = (n < MDIM) ? f2bf(Key[(size_t)(k0 + j) * MDIM + n]) : (short)0;
        *(short8*)(Keyfrag + (size_t)i * 8) = v;
    }
}

// k1: one wave per b, 2-deep Kt gather ping-pong (16 b128 loads in flight).
// NO register-count launch bound — R8 showed capping VGPR spills the pipeline
// buffers to scratch (WRITE_SIZE 12.8->77MB, dur 37->67us). Let VGPR float.
__global__ __launch_bounds__(64)
void k1_attkey(const int* __restrict__ input_u, const int* __restrict__ input_uf,
               const float* __restrict__ uidW, const short* __restrict__ Keyfrag,
               float* __restrict__ att_key, float* __restrict__ Ssum,
               int user_num)
{
    __shared__ float uidn[EDIM];   // 512 B
    __shared__ float invL[64];     // 256 B
    const int l = threadIdx.x;
    const int b = blockIdx.x;

    // earliest loads first so their waits don't drain the gather queue
    const int u = input_u[b];
    int ufv = (l < NFR) ? input_uf[(size_t)b * NFR + l] : user_num;
    float x0 = uidW[(size_t)u * EDIM + l];
    float x1 = uidW[(size_t)u * EDIM + 64 + l];

    // friend ids for my 4 A-frag rows: f = Mt*16 + (l&15)
    // (rows 50..63 -> some uidW row; their MFMA output rows are discarded)
    int fid[4];
    #pragma unroll
    for (int Mt = 0; Mt < 4; ++Mt)
        fid[Mt] = __shfl(ufv, Mt * 16 + (l & 15), 64);
    const int eo = (l >> 4) * 8;    // my k-octet within each 32-wide K block

    float4 gaA[4], gbA[4], gaB[4], gbB[4];
    // issue Kt=0 gathers + Keyfrag loads up front
    #pragma unroll
    for (int Mt = 0; Mt < 4; ++Mt) {
        const float* fp = uidW + (size_t)fid[Mt] * EDIM + eo;
        gaA[Mt] = *(const float4*)fp;
        gbA[Mt] = *(const float4*)(fp + 4);
    }
    short8 kb0 = *(const short8*)(Keyfrag + (size_t)(0 * 64 + l) * 8);
    short8 kb1 = *(const short8*)(Keyfrag + (size_t)(1 * 64 + l) * 8);
    short8 kb2 = *(const short8*)(Keyfrag + (size_t)(2 * 64 + l) * 8);
    short8 kb3 = *(const short8*)(Keyfrag + (size_t)(3 * 64 + l) * 8);

    // uid L2-normalize (overlaps with the in-flight gathers)
    float s = waveReduceSum(x0 * x0 + x1 * x1);
    float uinv = 1.0f / fmaxf(sqrtf(s), 1e-12f);
    uidn[l] = x0 * uinv;
    uidn[64 + l] = x1 * uinv;
    __builtin_amdgcn_wave_barrier();

    f32x4 acc[4];
    #pragma unroll
    for (int Mt = 0; Mt < 4; ++Mt) acc[Mt] = (f32x4){0.f, 0.f, 0.f, 0.f};
    float fss[4] = {0.f, 0.f, 0.f, 0.f};

    auto issue = [&](int Kt, float4 (&ga)[4], float4 (&gb)[4]) {
        #pragma unroll
        for (int Mt = 0; Mt < 4; ++Mt) {
            const float* fp = uidW + (size_t)fid[Mt] * EDIM + Kt * 32 + eo;
            ga[Mt] = *(const float4*)fp;
            gb[Mt] = *(const float4*)(fp + 4);
        }
    };
    auto comp = [&](int Kt, short8 kbv, float4 (&ga)[4], float4 (&gb)[4]) {
        float4 un0 = *(const float4*)&uidn[Kt * 32 + eo];
        float4 un1 = *(const float4*)&uidn[Kt * 32 + eo + 4];
        float4 kpa, kpb;
        kpa.x = un0.x * bf2f(kbv[0]); kpa.y = un0.y * bf2f(kbv[1]);
        kpa.z = un0.z * bf2f(kbv[2]); kpa.w = un0.w * bf2f(kbv[3]);
        kpb.x = un1.x * bf2f(kbv[4]); kpb.y = un1.y * bf2f(kbv[5]);
        kpb.z = un1.z * bf2f(kbv[6]); kpb.w = un1.w * bf2f(kbv[7]);
        short8 kbp = pack8(kpa, kpb);
        #pragma unroll
        for (int Mt = 0; Mt < 4; ++Mt) {
            fss[Mt] += ga[Mt].x*ga[Mt].x + ga[Mt].y*ga[Mt].y
                     + ga[Mt].z*ga[Mt].z + ga[Mt].w*ga[Mt].w
                     + gb[Mt].x*gb[Mt].x + gb[Mt].y*gb[Mt].y
                     + gb[Mt].z*gb[Mt].z + gb[Mt].w*gb[Mt].w;
            short8 a = pack8(ga[Mt], gb[Mt]);
            acc[Mt] = __builtin_amdgcn_mfma_f32_16x16x32_bf16(a, kbp, acc[Mt], 0, 0, 0);
        }
    };

    issue(1, gaB, gbB);
    comp(0, kb0, gaA, gbA);
    issue(2, gaA, gbA);
    comp(1, kb1, gaB, gbB);
    issue(3, gaB, gbB);
    comp(2, kb2, gaA, gbA);
    comp(3, kb3, gaB, gbB);

    // per-row 1/||fe|| with mask folded in; route to output-row lanes via LDS
    #pragma unroll
    for (int Mt = 0; Mt < 4; ++Mt) {
        float t = fss[Mt];
        t += __shfl_xor(t, 16, 64);
        t += __shfl_xor(t, 32, 64);
        int f = Mt * 16 + (l & 15);
        float fn = (f < NFR && fid[Mt] != user_num) ? 1.f : 0.f;
        invL[f] = fn / fmaxf(sqrtf(t), 1e-12f);   // 4 same-value writers, benign
    }
    __builtin_amdgcn_wave_barrier();

    const int m = l & 15;
    if (m < MDIM) {
        float* Ss = Ssum + (size_t)(b & (NSLICE - 1)) * NCOL;
        #pragma unroll
        for (int Mt = 0; Mt < 4; ++Mt) {
            const int fbase = Mt * 16 + (l >> 4) * 4;
            #pragma unroll
            for (int r = 0; r < 4; ++r) {
                int f = fbase + r;
                if (f < NFR) {
                    float val = acc[Mt][r] * invL[f];
                    att_key[((size_t)b * NFR + f) * MDIM + m] = val;
                    // masked rows -> val==0 -> exp(0)=1, matching reference
                    // softmax(axis=0) denominator semantics
                    atomicAdd(&Ss[f * MDIM + m], __expf(val));
                }
            }
        }
    }
}

// k2b: merge NSLICE partials per column -> inv denominator
__global__ __launch_bounds__(256)
void k2b_merge(const float* __restrict__ Ssum, float* __restrict__ ise)
{
    int col = blockIdx.x * 256 + threadIdx.x;
    if (col >= NCOL) return;
    float S = 0.f;
    #pragma unroll
    for (int s = 0; s < NSLICE; ++s) S += Ssum[s * NCOL + col];
    ise[col] = 1.0f / S;
}

// k3: wave-per-b, barrier-free (R6-proven, UNCHANGED). am -> f2 frag ->
// 64 MFMAs -> fold -> j -> friend sum -> score.
__global__ __launch_bounds__(256, 2)
void k3_final(const int* __restrict__ input_u, const int* __restrict__ input_i,
              const int* __restrict__ input_uf, const float* __restrict__ uidW,
              const float* __restrict__ iidW, const float* __restrict__ i_bias,
              const float* __restrict__ Mem, const short* __restrict__ WAfrag,
              const float* __restrict__ BA, const float* __restrict__ U_omega,
              const float* __restrict__ att_key, const float* __restrict__ ise,
              float* __restrict__ out, int user_num, int B)
{
    __shared__ short f2F4[4][64 * EDIM];   // 64 KB
    __shared__ float amL4[4][NCOL];        // 6.25 KB
    __shared__ float jxL4[4][64];          // 1 KB
    const int w = threadIdx.x >> 6, l = threadIdx.x & 63;
    const int b = blockIdx.x * 4 + w;
    if (b >= B) return;
    short* f2F = f2F4[w];
    float* amL = amL4[w];
    float* jxL = jxL4[w];

    const int u = input_u[b];
    const int ii = input_i[b];
    const float ib = i_bias[ii];
    int ufv = (l < NFR) ? input_uf[(size_t)b * NFR + l] : user_num;

    const int kg = l & 15, fl = l >> 4;
    const int e0 = kg * 8;

    // am = fn * exp(att_key) * ise  (max-free)
    #pragma unroll
    for (int c = 0; c < 7; ++c) {
        int i = l + 64 * c;
        if (i < NCOL) {
            float ak = att_key[(size_t)b * NCOL + i];
            int fid = __shfl(ufv, i >> 3, 64);
            amL[i] = (fid != user_num) ? __expf(ak) * ise[i] : 0.f;
        }
    }

    float4 mA[MDIM], mB[MDIM];            // Mem slice for this lane's e-octet
    #pragma unroll
    for (int m = 0; m < MDIM; ++m) {
        mA[m] = *(const float4*)&Mem[m * EDIM + e0];
        mB[m] = *(const float4*)&Mem[m * EDIM + e0 + 4];
    }
    __builtin_amdgcn_wave_barrier();

    // phase 1: f2 = (am x Mem) * fe -> swizzled frag (all 64 rows written)
    // f = 16*hi + 4*lo + fl; per-(hi,lo) affine LDS offsets
    #pragma unroll
    for (int hi = 0; hi < 4; ++hi) {
        #pragma unroll
        for (int lo = 0; lo < 4; ++lo) {
            int f = hi * 16 + lo * 4 + fl;
            short8 outv = {0, 0, 0, 0, 0, 0, 0, 0};
            if (f < NFR) {
                int fid = __shfl(ufv, f, 64);
                const float* fp = uidW + (size_t)fid * EDIM + e0;
                float4 g0 = *(const float4*)fp;
                float4 g1 = *(const float4*)(fp + 4);
                float4 am0 = *(const float4*)&amL[f * 8];
                float4 am1 = *(const float4*)&amL[f * 8 + 4];
                float4 fa = {0.f, 0.f, 0.f, 0.f}, fb = {0.f, 0.f, 0.f, 0.f};
                #pragma unroll
                for (int m = 0; m < 4; ++m) {
                    float c0 = (&am0.x)[m], c1 = (&am1.x)[m];
                    fa.x += c0 * mA[m].x + c1 * mA[m + 4].x;
                    fa.y += c0 * mA[m].y + c1 * mA[m + 4].y;
                    fa.z += c0 * mA[m].z + c1 * mA[m + 4].z;
                    fa.w += c0 * mA[m].w + c1 * mA[m + 4].w;
                    fb.x += c0 * mB[m].x + c1 * mB[m + 4].x;
                    fb.y += c0 * mB[m].y + c1 * mB[m + 4].y;
                    fb.z += c0 * mB[m].z + c1 * mB[m + 4].z;
                    fb.w += c0 * mB[m].w + c1 * mB[m + 4].w;
                }
                // masked friends: am==0 -> fa=fb=0 -> f2=0 (matches reference)
                float4 pA, pB;
                pA.x = fa.x * g0.x; pA.y = fa.y * g0.y;
                pA.z = fa.z * g0.z; pA.w = fa.w * g0.w;
                pB.x = fb.x * g1.x; pB.y = fb.y * g1.y;
                pB.z = fb.z * g1.z; pB.w = fb.w * g1.w;
                outv = pack8(pA, pB);
            }
            *(short8*)&f2F[fragOff(f, e0)] = outv;
        }
    }
    __builtin_amdgcn_wave_barrier();

    // phase 2: h = f2(64x128) x WA(128x64), 64 MFMAs per wave
    const int sl = slotR(l);
    f32x4 acc[4][4];
    #pragma unroll
    for (int Mt = 0; Mt < 4; ++Mt)
        #pragma unroll
        for (int Nt = 0; Nt < 4; ++Nt) acc[Mt][Nt] = (f32x4){0.f, 0.f, 0.f, 0.f};
    #pragma unroll
    for (int Kt = 0; Kt < 4; ++Kt) {
        short8 a[4];
        #pragma unroll
        for (int Mt = 0; Mt < 4; ++Mt)
            a[Mt] = *(const short8*)&f2F[(((Mt << 2) | Kt) * 64 + sl) * 8];
        #pragma unroll
        for (int Nt = 0; Nt < 4; ++Nt) {
            short8 bf = *(const short8*)(WAfrag + (size_t)(((Nt << 2) | Kt) * 64 + l) * 8);
            #pragma unroll
            for (int Mt = 0; Mt < 4; ++Mt)
                acc[Mt][Nt] = __builtin_amdgcn_mfma_f32_16x16x32_bf16(a[Mt], bf, acc[Mt][Nt], 0, 0, 0);
        }
    }

    // phase 3: fold relu(h+BA)*U_omega over all 64 cols -> per-friend p
    float ba4[4], uo4[4];
    #pragma unroll
    for (int Nt = 0; Nt < 4; ++Nt) {
        ba4[Nt] = BA[Nt * 16 + kg];
        uo4[Nt] = U_omega[Nt * 16 + kg];
    }
    float v[16];
    #pragma unroll
    for (int Mt = 0; Mt < 4; ++Mt)
        #pragma unroll
        for (int r = 0; r < 4; ++r) {
            float sv = 0.f;
            #pragma unroll
            for (int Nt = 0; Nt < 4; ++Nt)
                sv += fmaxf(acc[Mt][Nt][r] + ba4[Nt], 0.f) * uo4[Nt];
            v[Mt * 4 + r] = sv;
        }

    const bool c0 = l & 1, c1 = l & 2, c2 = l & 4, c3 = l & 8;
    #pragma unroll
    for (int k = 0; k < 8; ++k) {
        float lo = v[k], hi = v[k + 8];
        float send = c0 ? lo : hi;
        float recv = __shfl_xor(send, 1, 64);
        v[k] = c0 ? (hi + recv) : (lo + recv);
    }
    #pragma unroll
    for (int k = 0; k < 4; ++k) {
        float lo = v[k], hi = v[k + 4];
        float send = c1 ? lo : hi;
        float recv = __shfl_xor(send, 2, 64);
        v[k] = c1 ? (hi + recv) : (lo + recv);
    }
    #pragma unroll
    for (int k = 0; k < 2; ++k) {
        float lo = v[k], hi = v[k + 2];
        float send = c2 ? lo : hi;
        float recv = __shfl_xor(send, 4, 64);
        v[k] = c2 ? (hi + recv) : (lo + recv);
    }
    {
        float lo = v[0], hi = v[1];
        float send = c3 ? lo : hi;
        float recv = __shfl_xor(send, 8, 64);
        v[0] = c3 ? (hi + recv) : (lo + recv);
    }
    const int vIdx = ((l & 1) << 3) | ((l & 2) << 1) | ((l & 4) >> 1) | ((l & 8) >> 3);
    const int fLane = (vIdx >> 2) * 16 + (l >> 4) * 4 + (vIdx & 3);

    int ufF = __shfl(ufv, fLane, 64);
    float jv = 0.f;
    if (fLane < NFR && ufF != user_num) jv = __expf(v[0]);
    jxL[fLane] = jv;
    float winv = 1.0f / (waveReduceSum(jv) + 1e-8f);
    __builtin_amdgcn_wave_barrier();

    // phase 4: friend-weighted sum of f2 (pad rows are zero, jx pad = 0)
    float pa[8] = {0.f, 0.f, 0.f, 0.f, 0.f, 0.f, 0.f, 0.f};
    #pragma unroll
    for (int hi = 0; hi < 4; ++hi) {
        #pragma unroll
        for (int lo = 0; lo < 4; ++lo) {
            int f = hi * 16 + lo * 4 + fl;
            float jf = jxL[f];
            short8 vv = *(const short8*)&f2F[fragOff(f, e0)];
            #pragma unroll
            for (int j = 0; j < 8; ++j) pa[j] += jf * bf2f(vv[j]);
        }
    }
    #pragma unroll
    for (int j = 0; j < 8; ++j) {
        pa[j] += __shfl_xor(pa[j], 16, 64);
        pa[j] += __shfl_xor(pa[j], 32, 64);
    }

    // epilogue: score = sum_e (uid+friend)*iid + i_bias (4x duplicated -> *0.25)
    const float* up = uidW + (size_t)u * EDIM + e0;
    const float* ip = iidW + (size_t)ii * EDIM + e0;
    float4 u0 = *(const float4*)up;
    float4 u1 = *(const float4*)(up + 4);
    float4 i0 = *(const float4*)ip;
    float4 i1 = *(const float4*)(ip + 4);
    float sc = 0.f;
    #pragma unroll
    for (int j = 0; j < 4; ++j) {
        sc += ((&u0.x)[j] + pa[j] * winv) * (&i0.x)[j];
        sc += ((&u1.x)[j] + pa[j + 4] * winv) * (&i1.x)[j];
    }
    float red = waveReduceSum(sc);
    if (l == 0) out[b] = red * 0.25f + ib;
}

extern "C" void kernel_launch(void* const* d_in, const int* in_sizes, int n_in,
                              void* d_out, int out_size, void* d_ws, size_t ws_size,
                              hipStream_t stream)
{
    const int*   input_u  = (const int*)d_in[0];
    const int*   input_i  = (const int*)d_in[1];
    const int*   input_uf = (const int*)d_in[2];
    const float* uidW     = (const float*)d_in[3];
    const float* iidW     = (const float*)d_in[4];
    const float* i_bias   = (const float*)d_in[5];
    const float* Key      = (const float*)d_in[6];
    const float* Mem      = (const float*)d_in[7];
    const float* WA       = (const float*)d_in[8];
    const float* BA       = (const float*)d_in[9];
    const float* U_om     = (const float*)d_in[10];

    const int B = in_sizes[0];
    const int user_num = in_sizes[3] / EDIM - 1;

    float* att  = (float*)d_ws;                                  // B*400
    float* Ssum = att + (size_t)B * NCOL;                        // 64*400
    float* ise  = Ssum + NSLICE * NCOL;                          // 400
    short* WAfrag  = (short*)(ise + NCOL);                       // 8192
    short* Keyfrag = WAfrag + 4 * 4 * 64 * 8;                    // 2048

    const int nb3 = (B + 3) / 4;
    k0_prep<<<5, 256, 0, stream>>>(WA, Key, WAfrag, Keyfrag, Ssum);
    k1_attkey<<<B, 64, 0, stream>>>(input_u, input_uf, uidW, Keyfrag, att,
                                    Ssum, user_num);
    k2b_merge<<<2, 256, 0, stream>>>(Ssum, ise);
    k3_final<<<nb3, 256, 0, stream>>>(input_u, input_i, input_uf, uidW, iidW, i_bias,
                                      Mem, WAfrag, BA, U_om, att, ise,
                                      (float*)d_out, user_num, B);
}